// Round 6
// baseline (446.636 us; speedup 1.0000x reference)
//
#include <hip/hip_runtime.h>
#include <hip/hip_bf16.h>

typedef unsigned short ushort_t;
typedef __attribute__((ext_vector_type(8))) short bf16x8;
typedef __attribute__((ext_vector_type(4))) float f32x4;
typedef __attribute__((ext_vector_type(16))) float f32x16;
typedef __attribute__((ext_vector_type(4))) int i32x4;
typedef __attribute__((ext_vector_type(2))) int i32x2;

#define MFMA32(A, B, C) __builtin_amdgcn_mfma_f32_32x32x16_bf16(A, B, C, 0, 0, 0)

#if defined(__has_builtin)
#if __has_builtin(__builtin_amdgcn_exp2f)
#define EXP2(x) __builtin_amdgcn_exp2f(x)
#else
#define EXP2(x) exp2f(x)
#endif
#else
#define EXP2(x) exp2f(x)
#endif

// Workgroup barrier WITHOUT vmcnt(0) drain: LDS producer/consumer visibility
// only (lgkmcnt). Nontemporal global stores keep draining asynchronously.
#define LDS_BARRIER() asm volatile("s_waitcnt lgkmcnt(0)\n\ts_barrier" ::: "memory")

static constexpr int BATCH = 4;
static constexpr int DEP = 2048;
static constexpr int NH = 8;
static constexpr int CW = 128;   // per-head q/k/v width
static constexpr int HBn = 32;   // NH*BATCH
// log2(e)/sqrt(2048): folded into Q at projection so logits feed exp2 directly
static constexpr float QSCALE = (float)(1.4426950408889634 / 45.254833995939045);

static constexpr int PROW = 36;  // LDS P-tile row stride in ushorts (72B)

static __device__ __forceinline__ ushort_t f2bf(float f) {
  __hip_bfloat16 h = __float2bfloat16(f);
  return __builtin_bit_cast(ushort_t, h);
}
static __device__ __forceinline__ float bf2f(unsigned int u) {
  unsigned int v = (u & 0xffffu) << 16;
  return __builtin_bit_cast(float, v);
}
static __device__ __forceinline__ void nt_store4(float* p, f32x4 v) {
  __builtin_nontemporal_store(v, reinterpret_cast<f32x4*>(p));
}

// ---------------------------------------------------------------------------
// Kernel 1: pointwise QKV projection (Q pre-scaled by QSCALE). Unchanged.
//   q_ws/k_ws: bf16 [32 hb][2048 d][128 c];  vt_ws: bf16 [32 hb][128 c][2048 d]
// ---------------------------------------------------------------------------
__global__ __launch_bounds__(256) void proj_kernel(
    const float* __restrict__ feat,
    const float* __restrict__ Wq, const float* __restrict__ bq,
    const float* __restrict__ Wk, const float* __restrict__ bk,
    const float* __restrict__ Wv, const float* __restrict__ bv,
    ushort_t* __restrict__ q_ws, ushort_t* __restrict__ k_ws,
    ushort_t* __restrict__ vt_ws) {
  const int rt = blockIdx.x;
  const int iw = blockIdx.y >> 2;
  const int ct = blockIdx.y & 3;
  const float* W = (iw == 0) ? Wq : (iw == 1) ? Wk : Wv;
  const float* bs = (iw == 0) ? bq : (iw == 1) ? bk : bv;
  const int tid = threadIdx.x;

  __shared__ float fsm[32 * 64];
  __shared__ ushort_t re[32 * 256];

  {
    const float4* fg = reinterpret_cast<const float4*>(feat + (size_t)rt * 32 * 64);
    float4* fs = reinterpret_cast<float4*>(fsm);
    fs[tid] = fg[tid];
    fs[tid + 256] = fg[tid + 256];
  }
  __syncthreads();

  const int j = ct * 256 + tid;
  float acc[32];
  {
    const float b0 = bs[j];
#pragma unroll
    for (int r = 0; r < 32; ++r) acc[r] = b0;
  }
  for (int f4 = 0; f4 < 16; ++f4) {
    const float w0 = W[(f4 * 4 + 0) * 1024 + j];
    const float w1 = W[(f4 * 4 + 1) * 1024 + j];
    const float w2 = W[(f4 * 4 + 2) * 1024 + j];
    const float w3 = W[(f4 * 4 + 3) * 1024 + j];
#pragma unroll
    for (int r = 0; r < 32; ++r) {
      const float4 fv = *reinterpret_cast<const float4*>(&fsm[r * 64 + f4 * 4]);
      acc[r] = fmaf(fv.x, w0, acc[r]);
      acc[r] = fmaf(fv.y, w1, acc[r]);
      acc[r] = fmaf(fv.z, w2, acc[r]);
      acc[r] = fmaf(fv.w, w3, acc[r]);
    }
  }
  if (iw == 0) {
#pragma unroll
    for (int r = 0; r < 32; ++r) acc[r] *= QSCALE;
  }

  const int b = (rt * 32) >> 11;
  const int d0 = (rt * 32) & 2047;
  if (iw == 2) {
    const int h = j >> 7, cc = j & 127;
    ushort_t us[32];
#pragma unroll
    for (int r = 0; r < 32; ++r) us[r] = f2bf(acc[r]);
    ushort_t* dst = vt_ws + ((size_t)((h * BATCH + b) * CW + cc)) * DEP + d0;
#pragma unroll
    for (int i = 0; i < 4; ++i) {
      unsigned int a0 = us[8 * i + 0] | ((unsigned int)us[8 * i + 1] << 16);
      unsigned int a1 = us[8 * i + 2] | ((unsigned int)us[8 * i + 3] << 16);
      unsigned int a2 = us[8 * i + 4] | ((unsigned int)us[8 * i + 5] << 16);
      unsigned int a3 = us[8 * i + 6] | ((unsigned int)us[8 * i + 7] << 16);
      i32x4 v4 = {(int)a0, (int)a1, (int)a2, (int)a3};
      *reinterpret_cast<i32x4*>(dst + i * 8) = v4;
    }
  } else {
    ushort_t* wsb = (iw == 0) ? q_ws : k_ws;
#pragma unroll
    for (int r = 0; r < 32; ++r) re[r * 256 + tid] = f2bf(acc[r]);
    __syncthreads();
#pragma unroll
    for (int i = 0; i < 4; ++i) {
      const int id = tid + i * 256;
      const int r = id >> 5;
      const int c8 = (id & 31) * 8;
      const int jj = ct * 256 + c8;
      const int hh = jj >> 7, c2 = jj & 127;
      ushort_t* dst = wsb + ((size_t)((hh * BATCH + b) * DEP) + d0 + r) * CW + c2;
      *reinterpret_cast<i32x4*>(dst) = *reinterpret_cast<const i32x4*>(&re[r * 256 + c8]);
    }
  }
}

// ---------------------------------------------------------------------------
// Kernel 2: two-pass attention, split-c PV. 2048 blocks (32 hb x 64 q-tiles),
// 256 threads (4 waves). Wave w owns keys [w*512, w*512+512).
// Pass 1: QK^T + exp2 -> rowsums only. Pass 2 per 32-key step: QK^T again,
// normalized P -> bf16 LDS tile (PROW=36 row stride), coalesced nt attn
// writes, PV with wave-owned 32-channel c-slice reading all waves' tiles.
// In-loop barrier is lgkm-only: nt stores never drain inside the loop.
// P-tile layout: stag[buf][wave][q*PROW + key], key 0..31 ushorts.
// PV B-frag (32x32x16): lane (q,h) needs keys {16*kh + 8*h + 0..7}.
// ---------------------------------------------------------------------------
__global__ __launch_bounds__(256, 4) void attn_kernel(
    const ushort_t* __restrict__ q_ws, const ushort_t* __restrict__ k_ws,
    const ushort_t* __restrict__ vt_ws, float* __restrict__ out,
    float* __restrict__ attn) {
  __shared__ ushort_t stag[2][4][32 * PROW];  // [buf][wave][q*PROW + key]
  __shared__ float rsbuf[4][32];
  __shared__ float invbuf[32];

  // XCD swizzle: per XCD, blocks of one hb run back-to-back (L2 locality)
  const int bid0 = blockIdx.x;
  const int wg = (bid0 & 7) * 256 + (bid0 >> 3);
  const int hb = wg >> 6;
  const int qbase = (wg & 63) * 32;

  const int tid = threadIdx.x;
  const int w = tid >> 6, l = tid & 63;
  const int q = l & 31, h = l >> 5;

  // Q B-fragments: lane holds Q[f = fs*16 + h*8 + j][qbase+q]
  bf16x8 qf[8];
  {
    const ushort_t* qrow = q_ws + ((size_t)(hb * DEP + qbase + q)) * CW + h * 8;
#pragma unroll
    for (int fs = 0; fs < 8; ++fs)
      qf[fs] = *reinterpret_cast<const bf16x8*>(qrow + fs * 16);
  }

  const ushort_t* kbase =
      k_ws + (size_t)hb * DEP * CW + (size_t)q * CW + h * 8 + (size_t)(w * 512) * CW;

  // ---- pass 1: row sums ----
  float rs = 0.f;
  for (int t = 0; t < 16; ++t) {
    const ushort_t* krow = kbase + (size_t)(t * 32) * CW;
    bf16x8 ka[8];
#pragma unroll
    for (int fs = 0; fs < 8; ++fs)
      ka[fs] = *reinterpret_cast<const bf16x8*>(krow + fs * 16);
    f32x16 s = {};
#pragma unroll
    for (int fs = 0; fs < 8; ++fs) s = MFMA32(ka[fs], qf[fs], s);
#pragma unroll
    for (int r = 0; r < 16; ++r) rs += EXP2(s[r]);
  }
  rs += __shfl_xor(rs, 32);
  if (h == 0) rsbuf[w][q] = rs;
  __syncthreads();
  if (tid < 32)
    invbuf[tid] =
        1.f / ((rsbuf[0][tid] + rsbuf[1][tid]) + (rsbuf[2][tid] + rsbuf[3][tid]));
  __syncthreads();
  const float invq = invbuf[q];

  // ---- pass 2 ----
  ushort_t* mytile[2] = {&stag[0][w][0], &stag[1][w][0]};

  // s[r] holds S[key = (r&3) + 8*(r>>2) + 4h][q]; pairs (4i2..4i2+3) are
  // keys {8*i2 + 4h + 0..3} -> one 8B store per i2.
  auto STAGE = [&](int t, int buf) {
    const ushort_t* krow = kbase + (size_t)(t * 32) * CW;
    bf16x8 ka[8];
#pragma unroll
    for (int fs = 0; fs < 8; ++fs)
      ka[fs] = *reinterpret_cast<const bf16x8*>(krow + fs * 16);
    f32x16 s = {};
#pragma unroll
    for (int fs = 0; fs < 8; ++fs) s = MFMA32(ka[fs], qf[fs], s);
    ushort_t* tb = mytile[buf] + q * PROW + 4 * h;
#pragma unroll
    for (int i2 = 0; i2 < 4; ++i2) {
      const float p0 = EXP2(s[4 * i2 + 0]) * invq;
      const float p1 = EXP2(s[4 * i2 + 1]) * invq;
      const float p2 = EXP2(s[4 * i2 + 2]) * invq;
      const float p3 = EXP2(s[4 * i2 + 3]) * invq;
      const unsigned int pk0 =
          (unsigned int)f2bf(p0) | ((unsigned int)f2bf(p1) << 16);
      const unsigned int pk1 =
          (unsigned int)f2bf(p2) | ((unsigned int)f2bf(p3) << 16);
      i32x2 pw = {(int)pk0, (int)pk1};
      *reinterpret_cast<i32x2*>(tb + 8 * i2) = pw;
    }
  };

  f32x16 accO = {};
  float* attnbase = attn + (size_t)hb * DEP * DEP + (size_t)qbase * DEP;
  const ushort_t* vb =
      vt_ws + (size_t)hb * CW * DEP + (size_t)(w * 32 + q) * DEP + h * 8;

  STAGE(0, 0);
  LDS_BARRIER();

  for (int t = 0; t < 16; ++t) {
    const int buf = t & 1;
    if (t < 15) STAGE(t + 1, buf ^ 1);

    // attn write: own tile t -> rows qbase+0..31, cols w*512 + t*32 .. +32
    {
      const ushort_t* tb = mytile[buf];
      const int colb = w * 512 + t * 32 + (l & 7) * 4;
#pragma unroll
      for (int ii = 0; ii < 4; ++ii) {
        const int row = ii * 8 + (l >> 3);
        const i32x2 pr =
            *reinterpret_cast<const i32x2*>(tb + row * PROW + (l & 7) * 4);
        f32x4 v;
        v[0] = bf2f((unsigned int)pr[0]);
        v[1] = bf2f(((unsigned int)pr[0]) >> 16);
        v[2] = bf2f((unsigned int)pr[1]);
        v[3] = bf2f(((unsigned int)pr[1]) >> 16);
        nt_store4(attnbase + (size_t)row * DEP + colb, v);
      }
    }

    // PV: accO[c = w*32 + m][q] += sum over all 4 waves' staged tiles.
    // Lane (q,h) reads keys {16*kh + 8*h + 0..7} of row q (ushort units).
#pragma unroll
    for (int w2 = 0; w2 < 4; ++w2) {
      const ushort_t* tb = &stag[buf][w2][0] + q * PROW + 8 * h;
      const ushort_t* vchunk = vb + w2 * 512 + t * 32;
#pragma unroll
      for (int kh = 0; kh < 2; ++kh) {
        const i32x2 b0 = *reinterpret_cast<const i32x2*>(tb + 16 * kh);
        const i32x2 b1 = *reinterpret_cast<const i32x2*>(tb + 16 * kh + 4);
        i32x4 pbi = {b0[0], b0[1], b1[0], b1[1]};
        bf16x8 va = *reinterpret_cast<const bf16x8*>(vchunk + kh * 16);
        accO = MFMA32(va, __builtin_bit_cast(bf16x8, pbi), accO);
      }
    }
    LDS_BARRIER();
  }

  // ---- out store: lane owns col q, c-slice [w*32, w*32+32) ----
  {
    const int hh = hb >> 2, b = hb & 3;
#pragma unroll
    for (int r = 0; r < 16; ++r) {
      const int c = w * 32 + (r & 3) + 8 * (r >> 2) + 4 * h;
      out[((size_t)(b * 16 + hh * 2 + (c >> 6)) * DEP + qbase + q) * 64 + (c & 63)] =
          accO[r];
    }
  }
}

extern "C" void kernel_launch(void* const* d_in, const int* in_sizes, int n_in,
                              void* d_out, int out_size, void* d_ws, size_t ws_size,
                              hipStream_t stream) {
  const float* feat = (const float*)d_in[0];
  const float* Wq = (const float*)d_in[1];
  const float* bq = (const float*)d_in[2];
  const float* Wk = (const float*)d_in[3];
  const float* bk = (const float*)d_in[4];
  const float* Wv = (const float*)d_in[5];
  const float* bv = (const float*)d_in[6];

  ushort_t* q_ws = (ushort_t*)d_ws;
  ushort_t* k_ws = q_ws + (size_t)HBn * DEP * CW;
  ushort_t* vt_ws = k_ws + (size_t)HBn * DEP * CW;

  float* out = (float*)d_out;
  float* attn = out + (size_t)BATCH * 16 * DEP * 64;

  hipLaunchKernelGGL(proj_kernel, dim3(256, 12), dim3(256), 0, stream,
                     feat, Wq, bq, Wk, bk, Wv, bv, q_ws, k_ws, vt_ws);
  hipLaunchKernelGGL(attn_kernel, dim3(2048), dim3(256), 0, stream,
                     q_ws, k_ws, vt_ws, out, attn);
}